// Round 1
// baseline (301.461 us; speedup 1.0000x reference)
//
#include <hip/hip_runtime.h>

#define NN 2048
#define BB 4
#define DD 512
#define HH 8
#define DHH 64
#define RR 8192   // BB*NN

typedef __attribute__((ext_vector_type(8))) __bf16 bf16x8;
typedef __attribute__((ext_vector_type(4))) float f32x4;
typedef __attribute__((ext_vector_type(4))) unsigned int u32x4;

static __device__ __forceinline__ unsigned short f2bf(float f) {
  unsigned u = __builtin_bit_cast(unsigned, f);
  u += 0x7fffu + ((u >> 16) & 1u);
  return (unsigned short)(u >> 16);
}

// swizzled ushort index into a [rows][32] bf16 LDS tile (8-element granules)
static __device__ __forceinline__ int swz(int row, int col) {
  return (row * 32 + col) ^ (((row >> 1) & 3) << 3);
}

// ---------------- cast + reorder inputs: x,kv (N,B,D) fp32 -> [b*2048+n][D] bf16
__global__ __launch_bounds__(256) void cast_in_kernel(
    const float* __restrict__ x, const float* __restrict__ kv,
    unsigned short* __restrict__ xb, unsigned short* __restrict__ kvb) {
  const float* src = blockIdx.y ? kv : x;
  unsigned short* dst = blockIdx.y ? kvb : xb;
  int t = blockIdx.x * 256 + threadIdx.x;
  int o0 = t * 8;                       // output flat index, [b][n][d]
  int d = o0 & 511;
  int n = (o0 >> 9) & 2047;
  int b = o0 >> 20;
  const float* s = src + ((size_t)(n * BB + b) << 9) + d;
  f32x4 v0 = *(const f32x4*)s;
  f32x4 v1 = *(const f32x4*)(s + 4);
  union { unsigned short us[8]; u32x4 v; } o;
#pragma unroll
  for (int i = 0; i < 4; ++i) { o.us[i] = f2bf(v0[i]); o.us[4 + i] = f2bf(v1[i]); }
  *(u32x4*)(dst + o0) = o.v;
}

// ---------------- cast + transpose weights: W[k][o] fp32 -> WT[o][k] bf16 (512x512 each)
__global__ __launch_bounds__(256) void cast_w_kernel(
    const float* __restrict__ Wq, const float* __restrict__ Wkv, const float* __restrict__ Wo,
    unsigned short* __restrict__ WqT, unsigned short* __restrict__ WkvT, unsigned short* __restrict__ WoT) {
  const float* W = (blockIdx.y == 0) ? Wq : (blockIdx.y == 1) ? Wkv : Wo;
  unsigned short* WT = (blockIdx.y == 0) ? WqT : (blockIdx.y == 1) ? WkvT : WoT;
  int idx = blockIdx.x * 256 + threadIdx.x;  // 0..262143
  int o = idx & 511;
  int k = idx >> 9;
  WT[(size_t)o * 512 + k] = f2bf(W[(size_t)k * 512 + o]);
}

// ---------------- shared 128x128-tile GEMM, K=512, bf16 MFMA
// EPI 0: per-head LN -> q bf16 [b][h][n][64]
// EPI 1: cast -> kvp bf16 [b][h][m][64] AND kvpT bf16 [b][h][64][m]
// EPI 2: + bias -> fp32 [r][512]
template <int EPI>
__global__ __launch_bounds__(256) void gemm_kernel(
    const unsigned short* __restrict__ A,   // [8192][512] bf16
    const unsigned short* __restrict__ WT,  // [512 out][512 k] bf16
    const float* __restrict__ g,            // ln gamma (64) | bias (512)
    const float* __restrict__ beta,         // ln beta (64)
    unsigned short* __restrict__ out_bf,
    unsigned short* __restrict__ out_bf2,
    float* __restrict__ out_f32) {
  __shared__ unsigned short At[128 * 32];
  __shared__ unsigned short Bt[128 * 32];
  int tid = threadIdx.x;
  int w = tid >> 6, l = tid & 63, lr = l & 15, lh = l >> 4;
  int wr = w >> 1, wc = w & 1;
  int r0 = blockIdx.x * 128, c0 = blockIdx.y * 128;
  f32x4 acc[4][4] = {};
  for (int k0 = 0; k0 < 512; k0 += 32) {
#pragma unroll
    for (int p = 0; p < 2; ++p) {
      int flat = tid * 16 + p * 8;
      int row = flat >> 5, col = flat & 31;
      u32x4 va = *(const u32x4*)&A[(size_t)(r0 + row) * 512 + k0 + col];
      u32x4 vb = *(const u32x4*)&WT[(size_t)(c0 + row) * 512 + k0 + col];
      *(u32x4*)&At[swz(row, col)] = va;
      *(u32x4*)&Bt[swz(row, col)] = vb;
    }
    __syncthreads();
    bf16x8 a[4], b[4];
#pragma unroll
    for (int m = 0; m < 4; ++m)
      a[m] = *(const bf16x8*)&At[swz(wr * 64 + m * 16 + lr, lh * 8)];
#pragma unroll
    for (int n = 0; n < 4; ++n)
      b[n] = *(const bf16x8*)&Bt[swz(wc * 64 + n * 16 + lr, lh * 8)];
#pragma unroll
    for (int m = 0; m < 4; ++m)
#pragma unroll
      for (int n = 0; n < 4; ++n)
        acc[m][n] = __builtin_amdgcn_mfma_f32_16x16x32_bf16(a[m], b[n], acc[m][n], 0, 0, 0);
    __syncthreads();
  }
  int row_base = r0 + wr * 64;
  if (EPI == 0) {
    int h = (c0 + wc * 64) >> 6;
    float gq[4], bq[4];
#pragma unroll
    for (int n = 0; n < 4; ++n) { gq[n] = g[n * 16 + lr]; bq[n] = beta[n * 16 + lr]; }
#pragma unroll
    for (int m = 0; m < 4; ++m)
#pragma unroll
      for (int i = 0; i < 4; ++i) {
        float s1 = 0.f, s2 = 0.f;
#pragma unroll
        for (int n = 0; n < 4; ++n) { float v = acc[m][n][i]; s1 += v; s2 += v * v; }
#pragma unroll
        for (int off = 1; off < 16; off <<= 1) { s1 += __shfl_xor(s1, off); s2 += __shfl_xor(s2, off); }
        float mean = s1 * (1.f / 64.f);
        float var = s2 * (1.f / 64.f) - mean * mean;
        float rstd = rsqrtf(var + 1e-5f);
        int row = row_base + m * 16 + lh * 4 + i;
        int b = row >> 11, nidx = row & 2047;
        size_t obase = ((size_t)(b * HH + h) * NN + nidx) * DHH;
#pragma unroll
        for (int n = 0; n < 4; ++n) {
          float v = (acc[m][n][i] - mean) * rstd * gq[n] + bq[n];
          out_bf[obase + n * 16 + lr] = f2bf(v);
        }
      }
  } else if (EPI == 1) {
    int h = (c0 + wc * 64) >> 6;
#pragma unroll
    for (int m = 0; m < 4; ++m)
#pragma unroll
      for (int i = 0; i < 4; ++i) {
        int row = row_base + m * 16 + lh * 4 + i;
        int b = row >> 11, nidx = row & 2047;
        size_t obase = ((size_t)(b * HH + h) * NN + nidx) * DHH;
        size_t tbase = ((size_t)(b * HH + h) * DHH) * NN + nidx;
#pragma unroll
        for (int n = 0; n < 4; ++n) {
          unsigned short v = f2bf(acc[m][n][i]);
          int dh = n * 16 + lr;
          out_bf[obase + dh] = v;
          out_bf2[tbase + (size_t)dh * NN] = v;
        }
      }
  } else {
#pragma unroll
    for (int m = 0; m < 4; ++m)
#pragma unroll
      for (int i = 0; i < 4; ++i) {
        int row = row_base + m * 16 + lh * 4 + i;
#pragma unroll
        for (int n = 0; n < 4; ++n) {
          int col = c0 + wc * 64 + n * 16 + lr;
          out_f32[(size_t)row * 512 + col] = acc[m][n][i] + g[col];
        }
      }
  }
}

// ---------------- flash attention: per (b,h), QBLK=64 (4 waves x 16 rows), KVBLK=64
#define SCALE_L2E (0.125f * 1.44269504088896340736f)

__global__ __launch_bounds__(256) void attn_kernel(
    const unsigned short* __restrict__ qb, const unsigned short* __restrict__ kb,
    const unsigned short* __restrict__ vtb, unsigned short* __restrict__ attn_out) {
  int qt = blockIdx.x;   // 0..31
  int bh = blockIdx.y;   // 0..31 = b*8+h
  int tid = threadIdx.x, w = tid >> 6, l = tid & 63, lr = l & 15, lh = l >> 4;
  const unsigned short* Q = qb + (size_t)bh * NN * DHH;
  const unsigned short* K = kb + (size_t)bh * NN * DHH;
  const unsigned short* VT = vtb + (size_t)bh * DHH * NN;
  int qr0 = qt * 64 + w * 16;
  bf16x8 aq[2];
#pragma unroll
  for (int kk = 0; kk < 2; ++kk)
    aq[kk] = *(const bf16x8*)&Q[(size_t)(qr0 + lr) * DHH + lh * 8 + kk * 32];
  float mrow[4], lrow[4];
  f32x4 o[4] = {};
#pragma unroll
  for (int i = 0; i < 4; ++i) { mrow[i] = -1e30f; lrow[i] = 0.f; }

  __shared__ unsigned short plds[4][16 * 64];

  for (int kt = 0; kt < 32; ++kt) {
    int kr0 = kt * 64;
    f32x4 s[4];
#pragma unroll
    for (int j = 0; j < 4; ++j) {
      f32x4 acc = {};
#pragma unroll
      for (int kk = 0; kk < 2; ++kk) {
        bf16x8 bk = *(const bf16x8*)&K[(size_t)(kr0 + j * 16 + lr) * DHH + lh * 8 + kk * 32];
        acc = __builtin_amdgcn_mfma_f32_16x16x32_bf16(aq[kk], bk, acc, 0, 0, 0);
      }
      s[j] = acc * SCALE_L2E;   // log2-domain scores
    }
    float mnew[4], corr[4];
#pragma unroll
    for (int i = 0; i < 4; ++i) {
      float v = fmaxf(fmaxf(s[0][i], s[1][i]), fmaxf(s[2][i], s[3][i]));
#pragma unroll
      for (int off = 1; off < 16; off <<= 1) v = fmaxf(v, __shfl_xor(v, off));
      mnew[i] = fmaxf(mrow[i], v);
      corr[i] = exp2f(mrow[i] - mnew[i]);
      mrow[i] = mnew[i];
    }
#pragma unroll
    for (int j = 0; j < 4; ++j)
#pragma unroll
      for (int i = 0; i < 4; ++i)
        s[j][i] = exp2f(s[j][i] - mnew[i]);
#pragma unroll
    for (int i = 0; i < 4; ++i) {
      float rsum = s[0][i] + s[1][i] + s[2][i] + s[3][i];
#pragma unroll
      for (int off = 1; off < 16; off <<= 1) rsum += __shfl_xor(rsum, off);
      lrow[i] = lrow[i] * corr[i] + rsum;
    }
#pragma unroll
    for (int jd = 0; jd < 4; ++jd)
#pragma unroll
      for (int i = 0; i < 4; ++i) o[jd][i] *= corr[i];
    // P -> LDS (bf16, XOR-swizzled rows) then reload as A-fragments
#pragma unroll
    for (int j = 0; j < 4; ++j)
#pragma unroll
      for (int i = 0; i < 4; ++i) {
        int row = lh * 4 + i, col = j * 16 + lr;
        plds[w][(row * 64 + col) ^ ((row & 7) << 3)] = f2bf(s[j][i]);
      }
    bf16x8 ap[2];
#pragma unroll
    for (int kk = 0; kk < 2; ++kk)
      ap[kk] = *(const bf16x8*)&plds[w][(lr * 64 + lh * 8 + kk * 32) ^ ((lr & 7) << 3)];
#pragma unroll
    for (int jd = 0; jd < 4; ++jd)
#pragma unroll
      for (int kk = 0; kk < 2; ++kk) {
        bf16x8 bv = *(const bf16x8*)&VT[(size_t)(jd * 16 + lr) * NN + kr0 + lh * 8 + kk * 32];
        o[jd] = __builtin_amdgcn_mfma_f32_16x16x32_bf16(ap[kk], bv, o[jd], 0, 0, 0);
      }
  }
  int b = bh >> 3, h = bh & 7;
#pragma unroll
  for (int jd = 0; jd < 4; ++jd)
#pragma unroll
    for (int i = 0; i < 4; ++i) {
      int nrow = qr0 + lh * 4 + i;
      size_t r = (size_t)b * NN + nrow;
      attn_out[r * 512 + h * 64 + jd * 16 + lr] = f2bf(o[jd][i] / lrow[i]);
    }
}

// ---------------- final LN over D=512 + ls scale + (b,n)->(n,b) reorder, fp32 out
__global__ __launch_bounds__(256) void lnout_kernel(
    const float* __restrict__ proj2, const float* __restrict__ g, const float* __restrict__ beta,
    const float* __restrict__ ls, float* __restrict__ out) {
  int w = threadIdx.x >> 6, l = threadIdx.x & 63;
  int row = blockIdx.x * 4 + w;   // b*2048+n
  const float* src = proj2 + (size_t)row * DD + l * 8;
  f32x4 v0 = *(const f32x4*)src;
  f32x4 v1 = *(const f32x4*)(src + 4);
  float s1 = 0.f, s2 = 0.f;
#pragma unroll
  for (int i = 0; i < 4; ++i) { s1 += v0[i] + v1[i]; s2 += v0[i] * v0[i] + v1[i] * v1[i]; }
#pragma unroll
  for (int off = 1; off < 64; off <<= 1) { s1 += __shfl_xor(s1, off); s2 += __shfl_xor(s2, off); }
  float mean = s1 * (1.f / 512.f);
  float var = s2 * (1.f / 512.f) - mean * mean;
  float rstd = rsqrtf(var + 1e-5f);
  int b = row >> 11, n = row & 2047;
  float* dst = out + ((size_t)n * BB + b) * DD + l * 8;
  f32x4 r0, r1;
#pragma unroll
  for (int i = 0; i < 4; ++i) {
    int c = l * 8 + i;
    r0[i] = ((v0[i] - mean) * rstd * g[c] + beta[c]) * ls[c];
    int c2 = c + 4;
    r1[i] = ((v1[i] - mean) * rstd * g[c2] + beta[c2]) * ls[c2];
  }
  *(f32x4*)dst = r0;
  *(f32x4*)(dst + 4) = r1;
}

extern "C" void kernel_launch(void* const* d_in, const int* in_sizes, int n_in,
                              void* d_out, int out_size, void* d_ws, size_t ws_size,
                              hipStream_t stream) {
  const float* x = (const float*)d_in[0];
  const float* kv = (const float*)d_in[1];
  const float* Wq = (const float*)d_in[2];
  const float* Wkv = (const float*)d_in[3];
  const float* lnqg = (const float*)d_in[4];
  const float* lnqb = (const float*)d_in[5];
  const float* Wo = (const float*)d_in[6];
  const float* bo = (const float*)d_in[7];
  const float* lnog = (const float*)d_in[8];
  const float* lnob = (const float*)d_in[9];
  const float* ls = (const float*)d_in[10];
  float* out = (float*)d_out;

  unsigned short* xb = (unsigned short*)d_ws;
  unsigned short* kvb = xb + (size_t)RR * DD;
  unsigned short* WqT = kvb + (size_t)RR * DD;
  unsigned short* WkvT = WqT + 512 * 512;
  unsigned short* WoT = WkvT + 512 * 512;
  unsigned short* qln = WoT + 512 * 512;          // [b][h][n][64]
  unsigned short* kvp = qln + (size_t)RR * DD;    // [b][h][m][64]
  unsigned short* kvpT = kvp + (size_t)RR * DD;   // [b][h][64][m]
  unsigned short* aout = kvpT + (size_t)RR * DD;  // [b*2048+n][512]
  float* proj2 = (float*)(aout + (size_t)RR * DD);

  cast_in_kernel<<<dim3(2048, 2), 256, 0, stream>>>(x, kv, xb, kvb);
  cast_w_kernel<<<dim3(1024, 3), 256, 0, stream>>>(Wq, Wkv, Wo, WqT, WkvT, WoT);
  gemm_kernel<0><<<dim3(64, 4), 256, 0, stream>>>(xb, WqT, lnqg, lnqb, qln, nullptr, nullptr);
  gemm_kernel<1><<<dim3(64, 4), 256, 0, stream>>>(kvb, WkvT, nullptr, nullptr, kvp, kvpT, nullptr);
  attn_kernel<<<dim3(32, 32), 256, 0, stream>>>(qln, kvp, kvpT, aout);
  gemm_kernel<2><<<dim3(64, 4), 256, 0, stream>>>(aout, WoT, bo, nullptr, nullptr, nullptr, proj2);
  lnout_kernel<<<dim3(2048), 256, 0, stream>>>(proj2, lnog, lnob, ls, out);
}